// Round 3
// baseline (357.744 us; speedup 1.0000x reference)
//
#include <hip/hip_runtime.h>
#include <hip/hip_bf16.h>
#include <math.h>

typedef __attribute__((ext_vector_type(8))) short bf16x8;
typedef __attribute__((ext_vector_type(4))) float f32x4;

#define D_MODEL 2048
#define R_DIM 512
#define N_HEADS 16
#define D_K 32
#define B_SZ 2
#define SEQ 2048
#define M_ROWS (B_SZ * SEQ)
#define N_QKV 1536
// log2(e) / sqrt(D_K) — folded into Wq/bq so attention does raw exp2(Q.K)
#define QSCALE 0.2550627231338903f

// async global->LDS 16B DMA (lane i lands at lds_base + i*16)
__device__ __forceinline__ void dma16(const void* g, void* l)
{
    __builtin_amdgcn_global_load_lds(
        (const __attribute__((address_space(1))) void*)g,
        (__attribute__((address_space(3))) void*)l, 16, 0, 0);
}

// pack two f32 -> one dword of 2 bf16 (lo = first arg). No builtin on gfx950.
__device__ __forceinline__ unsigned cvt_pk_bf16(float lo, float hi)
{
    unsigned r;
    asm("v_cvt_pk_bf16_f32 %0, %1, %2" : "=v"(r) : "v"(lo), "v"(hi));
    return r;
}

// ---------------------------------------------------------------------------
// One-time f32 -> bf16 conversion. 4 loads in flight per thread (was 1 —
// latency-bound at 936 GB/s). Exact divisibility: nthr = 256*256 = 65536,
// every section n4 (elements/4) is a multiple of 4*65536 or equals it.
// by: 0 Wq*QSCALE  1 Wk  2 Wv  3 Wo  4 x  5 bias_qkv & mask bias
// ---------------------------------------------------------------------------
__global__ __launch_bounds__(256) void cvt_inputs(
    const float* __restrict__ x,  __hip_bfloat16* __restrict__ xb,
    const float* __restrict__ Wq, const float* __restrict__ Wk,
    const float* __restrict__ Wv, const float* __restrict__ Wo,
    __hip_bfloat16* __restrict__ Wqkvb, __hip_bfloat16* __restrict__ Wob,
    const float* __restrict__ bq, const float* __restrict__ bk,
    const float* __restrict__ bv, float* __restrict__ bias_qkv,
    const int* __restrict__ mask, float* __restrict__ mbias)
{
    const int by = blockIdx.y;
    const int tid = blockIdx.x * blockDim.x + threadIdx.x;
    const int nthr = gridDim.x * blockDim.x;   // 65536
    if (by == 5) {
        for (int i = tid; i < N_QKV; i += nthr) {
            float v = (i < 512) ? bq[i] * QSCALE
                    : (i < 1024) ? bk[i - 512] : bv[i - 1024];
            bias_qkv[i] = v;
        }
        for (int i = tid; i < B_SZ * SEQ; i += nthr)
            mbias[i] = mask[i] ? 0.0f : -1e30f;
        return;
    }
    const float* src; __hip_bfloat16* dst; float sc = 1.0f; int n;
    switch (by) {
      case 0: src = Wq; dst = Wqkvb; sc = QSCALE; n = R_DIM * D_MODEL; break;
      case 1: src = Wk; dst = Wqkvb + (size_t)R_DIM * D_MODEL; n = R_DIM * D_MODEL; break;
      case 2: src = Wv; dst = Wqkvb + (size_t)2 * R_DIM * D_MODEL; n = R_DIM * D_MODEL; break;
      case 3: src = Wo; dst = Wob; n = D_MODEL * R_DIM; break;
      default: src = x;  dst = xb;  n = M_ROWS * D_MODEL; break;
    }
    const float4* s4 = (const float4*)src;
    ushort4* d4 = (ushort4*)dst;
    const int n4 = n >> 2;          // 262144 (W) or 4194304 (x)
    const int step = nthr * 4;      // 262144
    for (int i0 = tid; i0 < n4; i0 += step) {
        float4 f0 = s4[i0];
        float4 f1 = s4[i0 + nthr];
        float4 f2 = s4[i0 + 2 * nthr];
        float4 f3 = s4[i0 + 3 * nthr];
        union { ushort4 u; __hip_bfloat16 h[4]; } r0, r1, r2, r3;
        r0.h[0] = __float2bfloat16(f0.x * sc); r0.h[1] = __float2bfloat16(f0.y * sc);
        r0.h[2] = __float2bfloat16(f0.z * sc); r0.h[3] = __float2bfloat16(f0.w * sc);
        r1.h[0] = __float2bfloat16(f1.x * sc); r1.h[1] = __float2bfloat16(f1.y * sc);
        r1.h[2] = __float2bfloat16(f1.z * sc); r1.h[3] = __float2bfloat16(f1.w * sc);
        r2.h[0] = __float2bfloat16(f2.x * sc); r2.h[1] = __float2bfloat16(f2.y * sc);
        r2.h[2] = __float2bfloat16(f2.z * sc); r2.h[3] = __float2bfloat16(f2.w * sc);
        r3.h[0] = __float2bfloat16(f3.x * sc); r3.h[1] = __float2bfloat16(f3.y * sc);
        r3.h[2] = __float2bfloat16(f3.z * sc); r3.h[3] = __float2bfloat16(f3.w * sc);
        d4[i0]            = r0.u;
        d4[i0 + nthr]     = r1.u;
        d4[i0 + 2 * nthr] = r2.u;
        d4[i0 + 3 * nthr] = r3.u;
    }
}

// ---------------------------------------------------------------------------
// DMA-staged GEMM: C[M,N] = A[M,K] @ W[N,K]^T + bias[N]  (bf16 MFMA, f32 acc)
// BM=128, BN=64, BK=64. 4 waves, wave-tile 64Mx32N (4x2 accs, 16 MFMA/iter).
// (unchanged)
// ---------------------------------------------------------------------------
template<bool OUT_BF16>
__global__ __launch_bounds__(256, 4) void gemm_dma(
    const __hip_bfloat16* __restrict__ A,
    const __hip_bfloat16* __restrict__ W,
    const float* __restrict__ bias,
    void* __restrict__ Cv,
    int N, int K)
{
    __shared__ __hip_bfloat16 As[128 * 64];   // 16 KB, slot = row*8 + (c^(row&7))
    __shared__ __hip_bfloat16 Bs[64 * 64];    // 8 KB

    const int tid = threadIdx.x, lane = tid & 63, w = tid >> 6;
    const int l15 = lane & 15, q = lane >> 4;
    const int bm = blockIdx.y * 128, bn = blockIdx.x * 64;
    const int m_off = (w & 1) * 64, n_off = (w >> 1) * 32;

    const int lrow = lane >> 3;            // 0..7
    const int lc   = (lane & 7) ^ lrow;    // swizzled 16B-chunk within row

    f32x4 acc[4][2] = {};

    for (int kt = 0; kt < K; kt += 64) {
        if (kt) __syncthreads();           // all waves done reading prev tile
        #pragma unroll
        for (int j = 0; j < 4; j++) {      // A: 128 rows, 8 rows per issue
            int row = (w * 4 + j) * 8 + lrow;
            dma16(&A[(size_t)(bm + row) * K + kt + lc * 8], &As[(w * 4 + j) * 512]);
        }
        #pragma unroll
        for (int j = 0; j < 2; j++) {      // B: 64 rows
            int row = (w * 2 + j) * 8 + lrow;
            dma16(&W[(size_t)(bn + row) * K + kt + lc * 8], &Bs[(w * 2 + j) * 512]);
        }
        __syncthreads();                   // vmcnt drain + barrier

        #pragma unroll
        for (int ks = 0; ks < 2; ks++) {
            bf16x8 af[4], bf[2];
            #pragma unroll
            for (int t = 0; t < 4; t++) {
                int row = m_off + t * 16 + l15;
                af[t] = *(const bf16x8*)&As[row * 64 + (((ks * 4 + q) ^ (l15 & 7)) * 8)];
            }
            #pragma unroll
            for (int u = 0; u < 2; u++) {
                int row = n_off + u * 16 + l15;
                bf[u] = *(const bf16x8*)&Bs[row * 64 + (((ks * 4 + q) ^ (l15 & 7)) * 8)];
            }
            #pragma unroll
            for (int mt = 0; mt < 4; mt++)
                #pragma unroll
                for (int nt = 0; nt < 2; nt++)
                    acc[mt][nt] = __builtin_amdgcn_mfma_f32_16x16x32_bf16(
                        af[mt], bf[nt], acc[mt][nt], 0, 0, 0);
        }
    }

    #pragma unroll
    for (int mt = 0; mt < 4; mt++) {
        #pragma unroll
        for (int nt = 0; nt < 2; nt++) {
            int gm = bm + m_off + mt * 16 + q * 4;
            int gn = bn + n_off + nt * 16 + l15;
            float bv = bias[gn];
            #pragma unroll
            for (int r = 0; r < 4; r++) {
                float v = acc[mt][nt][r] + bv;
                if (OUT_BF16)
                    ((__hip_bfloat16*)Cv)[(size_t)(gm + r) * N + gn] = __float2bfloat16(v);
                else
                    ((float*)Cv)[(size_t)(gm + r) * N + gn] = v;
            }
        }
    }
}

// ---------------------------------------------------------------------------
// Flash attention v6 = v5 + K-split x2 for occupancy.
// Each block handles HALF the k-range (1024). Softmax here has no running
// max (additive mask bias only), so halves are ADDITIVE: blocks write f32
// numerators (Opart) + partial row sums (Rsum); combine_halves finishes
// (O0+O1)/(r0+r1). Grid 2048 -> 8 blocks/CU (LDS 8x19456 = 152KB fits),
// launch_bounds(256,8) (VGPR<=64, currently 48). setprio(1) around MFMA
// clusters (T5, +4-7% on independent-wave attn).
// ---------------------------------------------------------------------------
__global__ __launch_bounds__(256, 8) void flash_attn6(
    const __hip_bfloat16* __restrict__ QKV,
    const float* __restrict__ mbias,
    float* __restrict__ Opart,
    float* __restrict__ Rsum)
{
    __shared__ __hip_bfloat16 Ks[2][64 * 40];   // 10 KB
    __shared__ __hip_bfloat16 Vt[2][32 * 72];   // 9 KB (sigma-permuted cols)

    const int tid = threadIdx.x, lane = tid & 63, w = tid >> 6;
    const int l15 = lane & 15, qg = lane >> 4;

    // XCD-chunked swizzle (2048 % 8 == 0 -> bijective): each XCD gets 256
    // consecutive logical blocks = 8 full (b,h,half) groups (~1MB K/V) -> L2.
    const int nwg = (int)gridDim.x;
    const int swz = ((int)blockIdx.x & 7) * (nwg >> 3) + ((int)blockIdx.x >> 3);
    const int qt   = swz & 31;
    const int half = (swz >> 5) & 1;
    const int h    = (swz >> 6) & 15;
    const int b    = swz >> 10;
    const int q0 = qt * 64;
    const int kt0 = half << 10;                 // 0 or 1024
    const int kend = kt0 + (SEQ / 2);

    // Q fragment (B-operand of swapped QK^T): row q0+w*16+l15, d = qg*8..+7
    const bf16x8 qa = *(const bf16x8*)
        &QKV[(size_t)(b * SEQ + q0 + w * 16 + l15) * N_QKV + h * D_K + qg * 8];

    const int kv_k = tid >> 2, d0_k = (tid & 3) * 8;   // K staging coords
    const int kv_v = tid & 63, d0_v = (tid >> 6) * 8;  // V staging coords
    // sigma-permuted V column: kv = 32a+16hi+4g+r  ->  scol = 32a+8g+4hi+r
    const int scol_v = (kv_v & 32) + ((kv_v >> 2) & 3) * 8
                     + ((kv_v >> 4) & 1) * 4 + (kv_v & 3);

    const __hip_bfloat16* Kp = QKV + (size_t)b * SEQ * N_QKV + R_DIM + h * D_K;
    const __hip_bfloat16* Vp = QKV + (size_t)b * SEQ * N_QKV + 2 * R_DIM + h * D_K;
    const float* mb_base = mbias + b * SEQ;

    f32x4 oacc[2] = {};
    float rsum = 0.f;

    uint4 kregA, kregB, vregA, vregB;
    float4 mbA[4], mbB[4];

    // prologue: first tile of this half into register set A
    kregA = *(const uint4*)&Kp[(size_t)(kt0 + kv_k) * N_QKV + d0_k];
    vregA = *(const uint4*)&Vp[(size_t)(kt0 + kv_v) * N_QKV + d0_v];
    #pragma unroll
    for (int nt = 0; nt < 4; nt++)
        mbA[nt] = *(const float4*)&mb_base[kt0 + nt * 16 + qg * 4];

#define FA_EXP(SC, MB, PA, U0, U1)                                              \
    {                                                                           \
        float p0 = __builtin_amdgcn_exp2f(SC[0] + MB.x);                        \
        float p1 = __builtin_amdgcn_exp2f(SC[1] + MB.y);                        \
        float p2 = __builtin_amdgcn_exp2f(SC[2] + MB.z);                        \
        float p3 = __builtin_amdgcn_exp2f(SC[3] + MB.w);                        \
        rsum += (p0 + p1) + (p2 + p3);                                          \
        PA.u[U0] = cvt_pk_bf16(p0, p1);                                         \
        PA.u[U1] = cvt_pk_bf16(p2, p3);                                         \
    }

#define FA_ITER(KT, BUF, KREG, VREG, MB, KREGN, VREGN, MBN)                     \
    {                                                                           \
        /* stage current tile (regs loaded last iter) into LDS[BUF] */          \
        *(uint4*)&Ks[BUF][kv_k * 40 + d0_k] = KREG;                             \
        { union { uint4 u; __hip_bfloat16 hv[8]; } vv; vv.u = VREG;             \
          _Pragma("unroll")                                                     \
          for (int j = 0; j < 8; j++)                                           \
              Vt[BUF][(d0_v + j) * 72 + scol_v] = vv.hv[j]; }                   \
        __syncthreads();                                                        \
        /* prefetch next tile right after barrier: full-iter latency cover */   \
        if ((KT) + 64 < kend) {                                                 \
            KREGN = *(const uint4*)&Kp[(size_t)((KT) + 64 + kv_k) * N_QKV + d0_k]; \
            VREGN = *(const uint4*)&Vp[(size_t)((KT) + 64 + kv_v) * N_QKV + d0_v]; \
            _Pragma("unroll")                                                   \
            for (int nt = 0; nt < 4; nt++)                                      \
                MBN[nt] = *(const float4*)&mb_base[(KT) + 64 + nt * 16 + qg * 4]; \
        }                                                                       \
        /* swapped QK^T from LDS: lane holds P[q=l15][KT+nt*16+qg*4+r] */       \
        f32x4 sc0, sc1, sc2, sc3;                                               \
        __builtin_amdgcn_s_setprio(1);                                          \
        { bf16x8 kb = *(const bf16x8*)&Ks[BUF][( 0 + l15) * 40 + qg * 8];       \
          f32x4 z = {}; sc0 = __builtin_amdgcn_mfma_f32_16x16x32_bf16(kb, qa, z, 0, 0, 0); } \
        { bf16x8 kb = *(const bf16x8*)&Ks[BUF][(16 + l15) * 40 + qg * 8];       \
          f32x4 z = {}; sc1 = __builtin_amdgcn_mfma_f32_16x16x32_bf16(kb, qa, z, 0, 0, 0); } \
        { bf16x8 kb = *(const bf16x8*)&Ks[BUF][(32 + l15) * 40 + qg * 8];       \
          f32x4 z = {}; sc2 = __builtin_amdgcn_mfma_f32_16x16x32_bf16(kb, qa, z, 0, 0, 0); } \
        { bf16x8 kb = *(const bf16x8*)&Ks[BUF][(48 + l15) * 40 + qg * 8];       \
          f32x4 z = {}; sc3 = __builtin_amdgcn_mfma_f32_16x16x32_bf16(kb, qa, z, 0, 0, 0); } \
        __builtin_amdgcn_s_setprio(0);                                          \
        /* exp2 + pack: lane's own dwords ARE the PV A-frag under sigma */      \
        union { unsigned u[4]; bf16x8 v; } pa0, pa1;                            \
        FA_EXP(sc0, MB[0], pa0, 0, 1)                                           \
        FA_EXP(sc1, MB[1], pa0, 2, 3)                                           \
        FA_EXP(sc2, MB[2], pa1, 0, 1)                                           \
        FA_EXP(sc3, MB[3], pa1, 2, 3)                                           \
        /* PV: sigma-permuted Vt -> one b128 per operand */                     \
        __builtin_amdgcn_s_setprio(1);                                          \
        _Pragma("unroll")                                                       \
        for (int dt = 0; dt < 2; dt++) {                                        \
            const __hip_bfloat16* vrow = &Vt[BUF][(dt * 16 + l15) * 72];        \
            bf16x8 vb0 = *(const bf16x8*)&vrow[qg * 8];                         \
            bf16x8 vb1 = *(const bf16x8*)&vrow[32 + qg * 8];                    \
            oacc[dt] = __builtin_amdgcn_mfma_f32_16x16x32_bf16(pa0.v, vb0, oacc[dt], 0, 0, 0); \
            oacc[dt] = __builtin_amdgcn_mfma_f32_16x16x32_bf16(pa1.v, vb1, oacc[dt], 0, 0, 0); \
        }                                                                       \
        __builtin_amdgcn_s_setprio(0);                                          \
    }

    for (int kt = kt0; kt < kend; kt += 128) {
        FA_ITER(kt,      0, kregA, vregA, mbA, kregB, vregB, mbB)
        FA_ITER(kt + 64, 1, kregB, vregB, mbB, kregA, vregA, mbA)
    }
#undef FA_ITER
#undef FA_EXP

    // row sums: lane (l15,qg) holds partial of row l15 over its k-slice
    float s = rsum;
    s += __shfl_xor(s, 16, 64);
    s += __shfl_xor(s, 32, 64);   // all lanes: partial-half sum of row l15

    float* Rs = Rsum + (size_t)half * (B_SZ * N_HEADS * SEQ)
              + (size_t)(b * N_HEADS + h) * SEQ;
    if (qg == 0) Rs[q0 + w * 16 + l15] = s;

    // oacc layout: D[m=q][n=d]: row = qg*4+r, col = l15 (+16*dt). Numerators.
    float* Op = Opart + (size_t)half * M_ROWS * R_DIM;
    #pragma unroll
    for (int r = 0; r < 4; r++) {
        int row = q0 + w * 16 + qg * 4 + r;
        #pragma unroll
        for (int dt = 0; dt < 2; dt++) {
            Op[(size_t)(b * SEQ + row) * R_DIM + h * D_K + dt * 16 + l15] =
                oacc[dt][r];
        }
    }
}

// ---------------------------------------------------------------------------
// (O0+O1)/(r0+r1) -> bf16 AO. 2M outputs, float4-pair reads, ushort4 writes.
// ---------------------------------------------------------------------------
__global__ __launch_bounds__(256) void combine_halves(
    const float* __restrict__ Opart,
    const float* __restrict__ Rsum,
    __hip_bfloat16* __restrict__ O)
{
    const int i = blockIdx.x * blockDim.x + threadIdx.x;   // grid covers n4 exactly
    const int flat = i * 4;
    const int h    = (flat >> 5) & 15;
    const int rowg = flat >> 9;               // b*SEQ + row
    const int bb   = rowg >> 11;
    const int row  = rowg & (SEQ - 1);
    const int ridx = (bb * N_HEADS + h) * SEQ + row;
    float4 a = ((const float4*)Opart)[i];
    float4 c = ((const float4*)Opart)[i + (M_ROWS * R_DIM / 4)];
    float inv = 1.0f / (Rsum[ridx] + Rsum[ridx + B_SZ * N_HEADS * SEQ]);
    union { ushort4 u; __hip_bfloat16 hv[4]; } r;
    r.hv[0] = __float2bfloat16(a.x + c.x > 0 || true ? (a.x + c.x) * inv : 0.f);
    r.hv[0] = __float2bfloat16((a.x + c.x) * inv);
    r.hv[1] = __float2bfloat16((a.y + c.y) * inv);
    r.hv[2] = __float2bfloat16((a.z + c.z) * inv);
    r.hv[3] = __float2bfloat16((a.w + c.w) * inv);
    ((ushort4*)O)[i] = r.u;
}

// ---------------------------------------------------------------------------
extern "C" void kernel_launch(void* const* d_in, const int* in_sizes, int n_in,
                              void* d_out, int out_size, void* d_ws, size_t ws_size,
                              hipStream_t stream)
{
    const float* x  = (const float*)d_in[0];
    const float* Wq = (const float*)d_in[1];
    const float* bq = (const float*)d_in[2];
    const float* Wk = (const float*)d_in[3];
    const float* bk = (const float*)d_in[4];
    const float* Wv = (const float*)d_in[5];
    const float* bv = (const float*)d_in[6];
    const float* Wo = (const float*)d_in[7];
    const float* bo = (const float*)d_in[8];
    const int* mask = (const int*)d_in[9];
    float* out = (float*)d_out;

    // ws layout. Phase 1 (cvt, gemm1): xb[0,16M), Wqkvb[16M,22M), biasq.
    // Phase 2 (flash, combine, gemm2): xb/Wqkvb/biasq dead ->
    //   Opart f32 [0, 16.78M), AO bf16 [17M, 21M), Rsum [21M, 21.5M).
    // Live throughout: Wob [22M,24M), mbias [24M+8K), QKVb [25M,37M).
    char* p = (char*)d_ws;
    __hip_bfloat16* xb     = (__hip_bfloat16*)p;                       // 16 MB
    float*          Opart  = (float*)p;                                // 16.78 MB
    __hip_bfloat16* AO     = (__hip_bfloat16*)(p + (17u << 20));       // 4 MB
    float*          Rsum   = (float*)(p + (21u << 20));                // 512 KB
    __hip_bfloat16* Wqkvb  = (__hip_bfloat16*)(p + (16u << 20));       // 6 MB
    __hip_bfloat16* Wob    = (__hip_bfloat16*)(p + (22u << 20));       // 2 MB
    float*          biasq  = (float*)(p + (24u << 20));                // 6 KB
    float*          mbias  = (float*)(p + (24u << 20) + 8192);         // 16 KB
    __hip_bfloat16* QKVb   = (__hip_bfloat16*)(p + (25u << 20));       // 12 MB

    dim3 blk(256);
    hipLaunchKernelGGL(cvt_inputs, dim3(256, 6), blk, 0, stream,
                       x, xb, Wq, Wk, Wv, Wo, Wqkvb, Wob, bq, bk, bv, biasq, mask, mbias);
    hipLaunchKernelGGL((gemm_dma<true>), dim3(N_QKV / 64, M_ROWS / 128), blk, 0, stream,
                       xb, Wqkvb, biasq, QKVb, N_QKV, D_MODEL);
    hipLaunchKernelGGL(flash_attn6, dim3(B_SZ * N_HEADS * 2 * (SEQ / 64)), blk, 0, stream,
                       QKVb, mbias, Opart, Rsum);
    hipLaunchKernelGGL(combine_halves, dim3(M_ROWS * R_DIM / 4 / 256), blk, 0, stream,
                       Opart, Rsum, AO);
    hipLaunchKernelGGL((gemm_dma<false>), dim3(D_MODEL / 64, M_ROWS / 128), blk, 0, stream,
                       AO, Wob, bo, out, D_MODEL, R_DIM);
}

// Round 4
// 205.926 us; speedup vs baseline: 1.7372x; 1.7372x over previous
//
#include <hip/hip_runtime.h>
#include <hip/hip_bf16.h>
#include <math.h>

typedef __attribute__((ext_vector_type(8))) short bf16x8;
typedef __attribute__((ext_vector_type(4))) float f32x4;

#define D_MODEL 2048
#define R_DIM 512
#define N_HEADS 16
#define D_K 32
#define B_SZ 2
#define SEQ 2048
#define M_ROWS (B_SZ * SEQ)
#define N_QKV 1536
// log2(e) / sqrt(D_K) — folded into Wq/bq so attention does raw exp2(Q.K)
#define QSCALE 0.2550627231338903f

// async global->LDS 16B DMA (lane i lands at lds_base + i*16)
__device__ __forceinline__ void dma16(const void* g, void* l)
{
    __builtin_amdgcn_global_load_lds(
        (const __attribute__((address_space(1))) void*)g,
        (__attribute__((address_space(3))) void*)l, 16, 0, 0);
}

// pack two f32 -> one dword of 2 bf16 (lo = first arg). No builtin on gfx950.
__device__ __forceinline__ unsigned cvt_pk_bf16(float lo, float hi)
{
    unsigned r;
    asm("v_cvt_pk_bf16_f32 %0, %1, %2" : "=v"(r) : "v"(lo), "v"(hi));
    return r;
}

// ---------------------------------------------------------------------------
// One-time f32 -> bf16 conversion. 4 loads in flight per thread.
// by: 0 Wq*QSCALE  1 Wk  2 Wv  3 Wo  4 x  5 bias_qkv & mask bias
// ---------------------------------------------------------------------------
__global__ __launch_bounds__(256) void cvt_inputs(
    const float* __restrict__ x,  __hip_bfloat16* __restrict__ xb,
    const float* __restrict__ Wq, const float* __restrict__ Wk,
    const float* __restrict__ Wv, const float* __restrict__ Wo,
    __hip_bfloat16* __restrict__ Wqkvb, __hip_bfloat16* __restrict__ Wob,
    const float* __restrict__ bq, const float* __restrict__ bk,
    const float* __restrict__ bv, float* __restrict__ bias_qkv,
    const int* __restrict__ mask, float* __restrict__ mbias)
{
    const int by = blockIdx.y;
    const int tid = blockIdx.x * blockDim.x + threadIdx.x;
    const int nthr = gridDim.x * blockDim.x;   // 65536
    if (by == 5) {
        for (int i = tid; i < N_QKV; i += nthr) {
            float v = (i < 512) ? bq[i] * QSCALE
                    : (i < 1024) ? bk[i - 512] : bv[i - 1024];
            bias_qkv[i] = v;
        }
        for (int i = tid; i < B_SZ * SEQ; i += nthr)
            mbias[i] = mask[i] ? 0.0f : -1e30f;
        return;
    }
    const float* src; __hip_bfloat16* dst; float sc = 1.0f; int n;
    switch (by) {
      case 0: src = Wq; dst = Wqkvb; sc = QSCALE; n = R_DIM * D_MODEL; break;
      case 1: src = Wk; dst = Wqkvb + (size_t)R_DIM * D_MODEL; n = R_DIM * D_MODEL; break;
      case 2: src = Wv; dst = Wqkvb + (size_t)2 * R_DIM * D_MODEL; n = R_DIM * D_MODEL; break;
      case 3: src = Wo; dst = Wob; n = D_MODEL * R_DIM; break;
      default: src = x;  dst = xb;  n = M_ROWS * D_MODEL; break;
    }
    const float4* s4 = (const float4*)src;
    ushort4* d4 = (ushort4*)dst;
    const int n4 = n >> 2;          // 262144 (W) or 4194304 (x)
    const int step = nthr * 4;      // 262144
    for (int i0 = tid; i0 < n4; i0 += step) {
        float4 f0 = s4[i0];
        float4 f1 = s4[i0 + nthr];
        float4 f2 = s4[i0 + 2 * nthr];
        float4 f3 = s4[i0 + 3 * nthr];
        union { ushort4 u; __hip_bfloat16 h[4]; } r0, r1, r2, r3;
        r0.h[0] = __float2bfloat16(f0.x * sc); r0.h[1] = __float2bfloat16(f0.y * sc);
        r0.h[2] = __float2bfloat16(f0.z * sc); r0.h[3] = __float2bfloat16(f0.w * sc);
        r1.h[0] = __float2bfloat16(f1.x * sc); r1.h[1] = __float2bfloat16(f1.y * sc);
        r1.h[2] = __float2bfloat16(f1.z * sc); r1.h[3] = __float2bfloat16(f1.w * sc);
        r2.h[0] = __float2bfloat16(f2.x * sc); r2.h[1] = __float2bfloat16(f2.y * sc);
        r2.h[2] = __float2bfloat16(f2.z * sc); r2.h[3] = __float2bfloat16(f2.w * sc);
        r3.h[0] = __float2bfloat16(f3.x * sc); r3.h[1] = __float2bfloat16(f3.y * sc);
        r3.h[2] = __float2bfloat16(f3.z * sc); r3.h[3] = __float2bfloat16(f3.w * sc);
        d4[i0]            = r0.u;
        d4[i0 + nthr]     = r1.u;
        d4[i0 + 2 * nthr] = r2.u;
        d4[i0 + 3 * nthr] = r3.u;
    }
}

// ---------------------------------------------------------------------------
// DMA-staged GEMM: C[M,N] = A[M,K] @ W[N,K]^T + bias[N]  (bf16 MFMA, f32 acc)
// BM=128, BN=64, BK=64. 4 waves, wave-tile 64Mx32N (4x2 accs, 16 MFMA/iter).
// (unchanged)
// ---------------------------------------------------------------------------
template<bool OUT_BF16>
__global__ __launch_bounds__(256, 4) void gemm_dma(
    const __hip_bfloat16* __restrict__ A,
    const __hip_bfloat16* __restrict__ W,
    const float* __restrict__ bias,
    void* __restrict__ Cv,
    int N, int K)
{
    __shared__ __hip_bfloat16 As[128 * 64];   // 16 KB, slot = row*8 + (c^(row&7))
    __shared__ __hip_bfloat16 Bs[64 * 64];    // 8 KB

    const int tid = threadIdx.x, lane = tid & 63, w = tid >> 6;
    const int l15 = lane & 15, q = lane >> 4;
    const int bm = blockIdx.y * 128, bn = blockIdx.x * 64;
    const int m_off = (w & 1) * 64, n_off = (w >> 1) * 32;

    const int lrow = lane >> 3;            // 0..7
    const int lc   = (lane & 7) ^ lrow;    // swizzled 16B-chunk within row

    f32x4 acc[4][2] = {};

    for (int kt = 0; kt < K; kt += 64) {
        if (kt) __syncthreads();           // all waves done reading prev tile
        #pragma unroll
        for (int j = 0; j < 4; j++) {      // A: 128 rows, 8 rows per issue
            int row = (w * 4 + j) * 8 + lrow;
            dma16(&A[(size_t)(bm + row) * K + kt + lc * 8], &As[(w * 4 + j) * 512]);
        }
        #pragma unroll
        for (int j = 0; j < 2; j++) {      // B: 64 rows
            int row = (w * 2 + j) * 8 + lrow;
            dma16(&W[(size_t)(bn + row) * K + kt + lc * 8], &Bs[(w * 2 + j) * 512]);
        }
        __syncthreads();                   // vmcnt drain + barrier

        #pragma unroll
        for (int ks = 0; ks < 2; ks++) {
            bf16x8 af[4], bf[2];
            #pragma unroll
            for (int t = 0; t < 4; t++) {
                int row = m_off + t * 16 + l15;
                af[t] = *(const bf16x8*)&As[row * 64 + (((ks * 4 + q) ^ (l15 & 7)) * 8)];
            }
            #pragma unroll
            for (int u = 0; u < 2; u++) {
                int row = n_off + u * 16 + l15;
                bf[u] = *(const bf16x8*)&Bs[row * 64 + (((ks * 4 + q) ^ (l15 & 7)) * 8)];
            }
            #pragma unroll
            for (int mt = 0; mt < 4; mt++)
                #pragma unroll
                for (int nt = 0; nt < 2; nt++)
                    acc[mt][nt] = __builtin_amdgcn_mfma_f32_16x16x32_bf16(
                        af[mt], bf[nt], acc[mt][nt], 0, 0, 0);
        }
    }

    #pragma unroll
    for (int mt = 0; mt < 4; mt++) {
        #pragma unroll
        for (int nt = 0; nt < 2; nt++) {
            int gm = bm + m_off + mt * 16 + q * 4;
            int gn = bn + n_off + nt * 16 + l15;
            float bv = bias[gn];
            #pragma unroll
            for (int r = 0; r < 4; r++) {
                float v = acc[mt][nt][r] + bv;
                if (OUT_BF16)
                    ((__hip_bfloat16*)Cv)[(size_t)(gm + r) * N + gn] = __float2bfloat16(v);
                else
                    ((float*)Cv)[(size_t)(gm + r) * N + gn] = v;
            }
        }
    }
}

// ---------------------------------------------------------------------------
// Flash attention v7 = v6 K-split x2, launch_bounds REVERTED to (256,4).
// R3 lesson: (256,8) forced VGPR cap 64 -> allocator collapsed to 32 VGPR +
// per-iteration scratch spills (648 MB HBM writes, 211 us). The 2nd arg is a
// VGPR-cap promise, NOT an occupancy requirement: with (256,4) (48 VGPR, no
// spill) residency is resource-set: LDS 19456 B -> 8 blocks/CU, VGPR 48 ->
// 10 blocks/CU => grid 2048 still gives 8 blocks/CU.
// ---------------------------------------------------------------------------
__global__ __launch_bounds__(256, 4) void flash_attn7(
    const __hip_bfloat16* __restrict__ QKV,
    const float* __restrict__ mbias,
    float* __restrict__ Opart,
    float* __restrict__ Rsum)
{
    __shared__ __hip_bfloat16 Ks[2][64 * 40];   // 10 KB
    __shared__ __hip_bfloat16 Vt[2][32 * 72];   // 9 KB (sigma-permuted cols)

    const int tid = threadIdx.x, lane = tid & 63, w = tid >> 6;
    const int l15 = lane & 15, qg = lane >> 4;

    // XCD-chunked swizzle (2048 % 8 == 0 -> bijective)
    const int nwg = (int)gridDim.x;
    const int swz = ((int)blockIdx.x & 7) * (nwg >> 3) + ((int)blockIdx.x >> 3);
    const int qt   = swz & 31;
    const int half = (swz >> 5) & 1;
    const int h    = (swz >> 6) & 15;
    const int b    = swz >> 10;
    const int q0 = qt * 64;
    const int kt0 = half << 10;                 // 0 or 1024
    const int kend = kt0 + (SEQ / 2);

    // Q fragment (B-operand of swapped QK^T): row q0+w*16+l15, d = qg*8..+7
    const bf16x8 qa = *(const bf16x8*)
        &QKV[(size_t)(b * SEQ + q0 + w * 16 + l15) * N_QKV + h * D_K + qg * 8];

    const int kv_k = tid >> 2, d0_k = (tid & 3) * 8;   // K staging coords
    const int kv_v = tid & 63, d0_v = (tid >> 6) * 8;  // V staging coords
    // sigma-permuted V column: kv = 32a+16hi+4g+r  ->  scol = 32a+8g+4hi+r
    const int scol_v = (kv_v & 32) + ((kv_v >> 2) & 3) * 8
                     + ((kv_v >> 4) & 1) * 4 + (kv_v & 3);

    const __hip_bfloat16* Kp = QKV + (size_t)b * SEQ * N_QKV + R_DIM + h * D_K;
    const __hip_bfloat16* Vp = QKV + (size_t)b * SEQ * N_QKV + 2 * R_DIM + h * D_K;
    const float* mb_base = mbias + b * SEQ;

    f32x4 oacc[2] = {};
    float rsum = 0.f;

    uint4 kregA, kregB, vregA, vregB;
    float4 mbA[4], mbB[4];

    // prologue: first tile of this half into register set A
    kregA = *(const uint4*)&Kp[(size_t)(kt0 + kv_k) * N_QKV + d0_k];
    vregA = *(const uint4*)&Vp[(size_t)(kt0 + kv_v) * N_QKV + d0_v];
    #pragma unroll
    for (int nt = 0; nt < 4; nt++)
        mbA[nt] = *(const float4*)&mb_base[kt0 + nt * 16 + qg * 4];

#define FA_EXP(SC, MB, PA, U0, U1)                                              \
    {                                                                           \
        float p0 = __builtin_amdgcn_exp2f(SC[0] + MB.x);                        \
        float p1 = __builtin_amdgcn_exp2f(SC[1] + MB.y);                        \
        float p2 = __builtin_amdgcn_exp2f(SC[2] + MB.z);                        \
        float p3 = __builtin_amdgcn_exp2f(SC[3] + MB.w);                        \
        rsum += (p0 + p1) + (p2 + p3);                                          \
        PA.u[U0] = cvt_pk_bf16(p0, p1);                                         \
        PA.u[U1] = cvt_pk_bf16(p2, p3);                                         \
    }

#define FA_ITER(KT, BUF, KREG, VREG, MB, KREGN, VREGN, MBN)                     \
    {                                                                           \
        /* stage current tile (regs loaded last iter) into LDS[BUF] */          \
        *(uint4*)&Ks[BUF][kv_k * 40 + d0_k] = KREG;                             \
        { union { uint4 u; __hip_bfloat16 hv[8]; } vv; vv.u = VREG;             \
          _Pragma("unroll")                                                     \
          for (int j = 0; j < 8; j++)                                           \
              Vt[BUF][(d0_v + j) * 72 + scol_v] = vv.hv[j]; }                   \
        __syncthreads();                                                        \
        /* prefetch next tile right after barrier: full-iter latency cover */   \
        if ((KT) + 64 < kend) {                                                 \
            KREGN = *(const uint4*)&Kp[(size_t)((KT) + 64 + kv_k) * N_QKV + d0_k]; \
            VREGN = *(const uint4*)&Vp[(size_t)((KT) + 64 + kv_v) * N_QKV + d0_v]; \
            _Pragma("unroll")                                                   \
            for (int nt = 0; nt < 4; nt++)                                      \
                MBN[nt] = *(const float4*)&mb_base[(KT) + 64 + nt * 16 + qg * 4]; \
        }                                                                       \
        /* swapped QK^T from LDS: lane holds P[q=l15][KT+nt*16+qg*4+r] */       \
        f32x4 sc0, sc1, sc2, sc3;                                               \
        __builtin_amdgcn_s_setprio(1);                                          \
        { bf16x8 kb = *(const bf16x8*)&Ks[BUF][( 0 + l15) * 40 + qg * 8];       \
          f32x4 z = {}; sc0 = __builtin_amdgcn_mfma_f32_16x16x32_bf16(kb, qa, z, 0, 0, 0); } \
        { bf16x8 kb = *(const bf16x8*)&Ks[BUF][(16 + l15) * 40 + qg * 8];       \
          f32x4 z = {}; sc1 = __builtin_amdgcn_mfma_f32_16x16x32_bf16(kb, qa, z, 0, 0, 0); } \
        { bf16x8 kb = *(const bf16x8*)&Ks[BUF][(32 + l15) * 40 + qg * 8];       \
          f32x4 z = {}; sc2 = __builtin_amdgcn_mfma_f32_16x16x32_bf16(kb, qa, z, 0, 0, 0); } \
        { bf16x8 kb = *(const bf16x8*)&Ks[BUF][(48 + l15) * 40 + qg * 8];       \
          f32x4 z = {}; sc3 = __builtin_amdgcn_mfma_f32_16x16x32_bf16(kb, qa, z, 0, 0, 0); } \
        __builtin_amdgcn_s_setprio(0);                                          \
        /* exp2 + pack: lane's own dwords ARE the PV A-frag under sigma */      \
        union { unsigned u[4]; bf16x8 v; } pa0, pa1;                            \
        FA_EXP(sc0, MB[0], pa0, 0, 1)                                           \
        FA_EXP(sc1, MB[1], pa0, 2, 3)                                           \
        FA_EXP(sc2, MB[2], pa1, 0, 1)                                           \
        FA_EXP(sc3, MB[3], pa1, 2, 3)                                           \
        /* PV: sigma-permuted Vt -> one b128 per operand */                     \
        __builtin_amdgcn_s_setprio(1);                                          \
        _Pragma("unroll")                                                       \
        for (int dt = 0; dt < 2; dt++) {                                        \
            const __hip_bfloat16* vrow = &Vt[BUF][(dt * 16 + l15) * 72];        \
            bf16x8 vb0 = *(const bf16x8*)&vrow[qg * 8];                         \
            bf16x8 vb1 = *(const bf16x8*)&vrow[32 + qg * 8];                    \
            oacc[dt] = __builtin_amdgcn_mfma_f32_16x16x32_bf16(pa0.v, vb0, oacc[dt], 0, 0, 0); \
            oacc[dt] = __builtin_amdgcn_mfma_f32_16x16x32_bf16(pa1.v, vb1, oacc[dt], 0, 0, 0); \
        }                                                                       \
        __builtin_amdgcn_s_setprio(0);                                          \
    }

    for (int kt = kt0; kt < kend; kt += 128) {
        FA_ITER(kt,      0, kregA, vregA, mbA, kregB, vregB, mbB)
        FA_ITER(kt + 64, 1, kregB, vregB, mbB, kregA, vregA, mbA)
    }
#undef FA_ITER
#undef FA_EXP

    // row sums: lane (l15,qg) holds partial of row l15 over its k-slice
    float s = rsum;
    s += __shfl_xor(s, 16, 64);
    s += __shfl_xor(s, 32, 64);   // all lanes: partial-half sum of row l15

    float* Rs = Rsum + (size_t)half * (B_SZ * N_HEADS * SEQ)
              + (size_t)(b * N_HEADS + h) * SEQ;
    if (qg == 0) Rs[q0 + w * 16 + l15] = s;

    // oacc layout: D[m=q][n=d]: row = qg*4+r, col = l15 (+16*dt). Numerators.
    float* Op = Opart + (size_t)half * M_ROWS * R_DIM;
    #pragma unroll
    for (int r = 0; r < 4; r++) {
        int row = q0 + w * 16 + qg * 4 + r;
        #pragma unroll
        for (int dt = 0; dt < 2; dt++) {
            Op[(size_t)(b * SEQ + row) * R_DIM + h * D_K + dt * 16 + l15] =
                oacc[dt][r];
        }
    }
}

// ---------------------------------------------------------------------------
// (O0+O1)/(r0+r1) -> bf16 AO. 2M outputs, float4-pair reads, ushort4 writes.
// ---------------------------------------------------------------------------
__global__ __launch_bounds__(256) void combine_halves(
    const float* __restrict__ Opart,
    const float* __restrict__ Rsum,
    __hip_bfloat16* __restrict__ O)
{
    const int i = blockIdx.x * blockDim.x + threadIdx.x;   // grid covers n4 exactly
    const int flat = i * 4;
    const int h    = (flat >> 5) & 15;
    const int rowg = flat >> 9;               // b*SEQ + row
    const int bb   = rowg >> 11;
    const int row  = rowg & (SEQ - 1);
    const int ridx = (bb * N_HEADS + h) * SEQ + row;
    float4 a = ((const float4*)Opart)[i];
    float4 c = ((const float4*)Opart)[i + (M_ROWS * R_DIM / 4)];
    float inv = 1.0f / (Rsum[ridx] + Rsum[ridx + B_SZ * N_HEADS * SEQ]);
    union { ushort4 u; __hip_bfloat16 hv[4]; } r;
    r.hv[0] = __float2bfloat16((a.x + c.x) * inv);
    r.hv[1] = __float2bfloat16((a.y + c.y) * inv);
    r.hv[2] = __float2bfloat16((a.z + c.z) * inv);
    r.hv[3] = __float2bfloat16((a.w + c.w) * inv);
    ((ushort4*)O)[i] = r.u;
}

// ---------------------------------------------------------------------------
extern "C" void kernel_launch(void* const* d_in, const int* in_sizes, int n_in,
                              void* d_out, int out_size, void* d_ws, size_t ws_size,
                              hipStream_t stream)
{
    const float* x  = (const float*)d_in[0];
    const float* Wq = (const float*)d_in[1];
    const float* bq = (const float*)d_in[2];
    const float* Wk = (const float*)d_in[3];
    const float* bk = (const float*)d_in[4];
    const float* Wv = (const float*)d_in[5];
    const float* bv = (const float*)d_in[6];
    const float* Wo = (const float*)d_in[7];
    const float* bo = (const float*)d_in[8];
    const int* mask = (const int*)d_in[9];
    float* out = (float*)d_out;

    // ws layout. Phase 1 (cvt, gemm1): xb[0,16M), Wqkvb[16M,22M), biasq.
    // Phase 2 (flash, combine, gemm2): xb/Wqkvb/biasq dead ->
    //   Opart f32 [0, 16.78M), AO bf16 [17M, 21M), Rsum [21M, 21.5M).
    // Live throughout: Wob [22M,24M), mbias [24M+8K), QKVb [25M,37M).
    char* p = (char*)d_ws;
    __hip_bfloat16* xb     = (__hip_bfloat16*)p;                       // 16 MB
    float*          Opart  = (float*)p;                                // 16.78 MB
    __hip_bfloat16* AO     = (__hip_bfloat16*)(p + (17u << 20));       // 4 MB
    float*          Rsum   = (float*)(p + (21u << 20));                // 512 KB
    __hip_bfloat16* Wqkvb  = (__hip_bfloat16*)(p + (16u << 20));       // 6 MB
    __hip_bfloat16* Wob    = (__hip_bfloat16*)(p + (22u << 20));       // 2 MB
    float*          biasq  = (float*)(p + (24u << 20));                // 6 KB
    float*          mbias  = (float*)(p + (24u << 20) + 8192);         // 16 KB
    __hip_bfloat16* QKVb   = (__hip_bfloat16*)(p + (25u << 20));       // 12 MB

    dim3 blk(256);
    hipLaunchKernelGGL(cvt_inputs, dim3(256, 6), blk, 0, stream,
                       x, xb, Wq, Wk, Wv, Wo, Wqkvb, Wob, bq, bk, bv, biasq, mask, mbias);
    hipLaunchKernelGGL((gemm_dma<true>), dim3(N_QKV / 64, M_ROWS / 128), blk, 0, stream,
                       xb, Wqkvb, biasq, QKVb, N_QKV, D_MODEL);
    hipLaunchKernelGGL(flash_attn7, dim3(B_SZ * N_HEADS * 2 * (SEQ / 64)), blk, 0, stream,
                       QKVb, mbias, Opart, Rsum);
    hipLaunchKernelGGL(combine_halves, dim3(M_ROWS * R_DIM / 4 / 256), blk, 0, stream,
                       Opart, Rsum, AO);
    hipLaunchKernelGGL((gemm_dma<false>), dim3(D_MODEL / 64, M_ROWS / 128), blk, 0, stream,
                       AO, Wob, bo, out, D_MODEL, R_DIM);
}

// Round 5
// 186.363 us; speedup vs baseline: 1.9196x; 1.1050x over previous
//
#include <hip/hip_runtime.h>
#include <hip/hip_bf16.h>
#include <math.h>

typedef __attribute__((ext_vector_type(8))) short bf16x8;
typedef __attribute__((ext_vector_type(4))) float f32x4;

#define D_MODEL 2048
#define R_DIM 512
#define N_HEADS 16
#define D_K 32
#define B_SZ 2
#define SEQ 2048
#define M_ROWS (B_SZ * SEQ)
#define N_QKV 1536
// log2(e) / sqrt(D_K) — folded into Wq/bq so attention does raw exp2(Q.K)
#define QSCALE 0.2550627231338903f

// async global->LDS 16B DMA (lane i lands at lds_base + i*16)
__device__ __forceinline__ void dma16(const void* g, void* l)
{
    __builtin_amdgcn_global_load_lds(
        (const __attribute__((address_space(1))) void*)g,
        (__attribute__((address_space(3))) void*)l, 16, 0, 0);
}

// pack two f32 -> one dword of 2 bf16 (lo = first arg). No builtin on gfx950.
__device__ __forceinline__ unsigned cvt_pk_bf16(float lo, float hi)
{
    unsigned r;
    asm("v_cvt_pk_bf16_f32 %0, %1, %2" : "=v"(r) : "v"(lo), "v"(hi));
    return r;
}

// ---------------------------------------------------------------------------
// One-time f32 -> bf16 conversion. 4 loads in flight per thread.
// by: 0 Wq*QSCALE  1 Wk  2 Wv  3 Wo  4 x  5 bias_qkv & mask bias
// ---------------------------------------------------------------------------
__global__ __launch_bounds__(256) void cvt_inputs(
    const float* __restrict__ x,  __hip_bfloat16* __restrict__ xb,
    const float* __restrict__ Wq, const float* __restrict__ Wk,
    const float* __restrict__ Wv, const float* __restrict__ Wo,
    __hip_bfloat16* __restrict__ Wqkvb, __hip_bfloat16* __restrict__ Wob,
    const float* __restrict__ bq, const float* __restrict__ bk,
    const float* __restrict__ bv, float* __restrict__ bias_qkv,
    const int* __restrict__ mask, float* __restrict__ mbias)
{
    const int by = blockIdx.y;
    const int tid = blockIdx.x * blockDim.x + threadIdx.x;
    const int nthr = gridDim.x * blockDim.x;   // 65536
    if (by == 5) {
        for (int i = tid; i < N_QKV; i += nthr) {
            float v = (i < 512) ? bq[i] * QSCALE
                    : (i < 1024) ? bk[i - 512] : bv[i - 1024];
            bias_qkv[i] = v;
        }
        for (int i = tid; i < B_SZ * SEQ; i += nthr)
            mbias[i] = mask[i] ? 0.0f : -1e30f;
        return;
    }
    const float* src; __hip_bfloat16* dst; float sc = 1.0f; int n;
    switch (by) {
      case 0: src = Wq; dst = Wqkvb; sc = QSCALE; n = R_DIM * D_MODEL; break;
      case 1: src = Wk; dst = Wqkvb + (size_t)R_DIM * D_MODEL; n = R_DIM * D_MODEL; break;
      case 2: src = Wv; dst = Wqkvb + (size_t)2 * R_DIM * D_MODEL; n = R_DIM * D_MODEL; break;
      case 3: src = Wo; dst = Wob; n = D_MODEL * R_DIM; break;
      default: src = x;  dst = xb;  n = M_ROWS * D_MODEL; break;
    }
    const float4* s4 = (const float4*)src;
    ushort4* d4 = (ushort4*)dst;
    const int n4 = n >> 2;          // 262144 (W) or 4194304 (x)
    const int step = nthr * 4;      // 262144
    for (int i0 = tid; i0 < n4; i0 += step) {
        float4 f0 = s4[i0];
        float4 f1 = s4[i0 + nthr];
        float4 f2 = s4[i0 + 2 * nthr];
        float4 f3 = s4[i0 + 3 * nthr];
        union { ushort4 u; __hip_bfloat16 h[4]; } r0, r1, r2, r3;
        r0.h[0] = __float2bfloat16(f0.x * sc); r0.h[1] = __float2bfloat16(f0.y * sc);
        r0.h[2] = __float2bfloat16(f0.z * sc); r0.h[3] = __float2bfloat16(f0.w * sc);
        r1.h[0] = __float2bfloat16(f1.x * sc); r1.h[1] = __float2bfloat16(f1.y * sc);
        r1.h[2] = __float2bfloat16(f1.z * sc); r1.h[3] = __float2bfloat16(f1.w * sc);
        r2.h[0] = __float2bfloat16(f2.x * sc); r2.h[1] = __float2bfloat16(f2.y * sc);
        r2.h[2] = __float2bfloat16(f2.z * sc); r2.h[3] = __float2bfloat16(f2.w * sc);
        r3.h[0] = __float2bfloat16(f3.x * sc); r3.h[1] = __float2bfloat16(f3.y * sc);
        r3.h[2] = __float2bfloat16(f3.z * sc); r3.h[3] = __float2bfloat16(f3.w * sc);
        d4[i0]            = r0.u;
        d4[i0 + nthr]     = r1.u;
        d4[i0 + 2 * nthr] = r2.u;
        d4[i0 + 3 * nthr] = r3.u;
    }
}

// ---------------------------------------------------------------------------
// DMA-staged GEMM: C[M,N] = A[M,K] @ W[N,K]^T + bias[N]  (bf16 MFMA, f32 acc)
// BM=128, BN=64, BK=64. 4 waves, wave-tile 64Mx32N (4x2 accs, 16 MFMA/iter).
// (unchanged)
// ---------------------------------------------------------------------------
template<bool OUT_BF16>
__global__ __launch_bounds__(256, 4) void gemm_dma(
    const __hip_bfloat16* __restrict__ A,
    const __hip_bfloat16* __restrict__ W,
    const float* __restrict__ bias,
    void* __restrict__ Cv,
    int N, int K)
{
    __shared__ __hip_bfloat16 As[128 * 64];   // 16 KB, slot = row*8 + (c^(row&7))
    __shared__ __hip_bfloat16 Bs[64 * 64];    // 8 KB

    const int tid = threadIdx.x, lane = tid & 63, w = tid >> 6;
    const int l15 = lane & 15, q = lane >> 4;
    const int bm = blockIdx.y * 128, bn = blockIdx.x * 64;
    const int m_off = (w & 1) * 64, n_off = (w >> 1) * 32;

    const int lrow = lane >> 3;            // 0..7
    const int lc   = (lane & 7) ^ lrow;    // swizzled 16B-chunk within row

    f32x4 acc[4][2] = {};

    for (int kt = 0; kt < K; kt += 64) {
        if (kt) __syncthreads();           // all waves done reading prev tile
        #pragma unroll
        for (int j = 0; j < 4; j++) {      // A: 128 rows, 8 rows per issue
            int row = (w * 4 + j) * 8 + lrow;
            dma16(&A[(size_t)(bm + row) * K + kt + lc * 8], &As[(w * 4 + j) * 512]);
        }
        #pragma unroll
        for (int j = 0; j < 2; j++) {      // B: 64 rows
            int row = (w * 2 + j) * 8 + lrow;
            dma16(&W[(size_t)(bn + row) * K + kt + lc * 8], &Bs[(w * 2 + j) * 512]);
        }
        __syncthreads();                   // vmcnt drain + barrier

        #pragma unroll
        for (int ks = 0; ks < 2; ks++) {
            bf16x8 af[4], bf[2];
            #pragma unroll
            for (int t = 0; t < 4; t++) {
                int row = m_off + t * 16 + l15;
                af[t] = *(const bf16x8*)&As[row * 64 + (((ks * 4 + q) ^ (l15 & 7)) * 8)];
            }
            #pragma unroll
            for (int u = 0; u < 2; u++) {
                int row = n_off + u * 16 + l15;
                bf[u] = *(const bf16x8*)&Bs[row * 64 + (((ks * 4 + q) ^ (l15 & 7)) * 8)];
            }
            #pragma unroll
            for (int mt = 0; mt < 4; mt++)
                #pragma unroll
                for (int nt = 0; nt < 2; nt++)
                    acc[mt][nt] = __builtin_amdgcn_mfma_f32_16x16x32_bf16(
                        af[mt], bf[nt], acc[mt][nt], 0, 0, 0);
        }
    }

    #pragma unroll
    for (int mt = 0; mt < 4; mt++) {
        #pragma unroll
        for (int nt = 0; nt < 2; nt++) {
            int gm = bm + m_off + mt * 16 + q * 4;
            int gn = bn + n_off + nt * 16 + l15;
            float bv = bias[gn];
            #pragma unroll
            for (int r = 0; r < 4; r++) {
                float v = acc[mt][nt][r] + bv;
                if (OUT_BF16)
                    ((__hip_bfloat16*)Cv)[(size_t)(gm + r) * N + gn] = __float2bfloat16(v);
                else
                    ((float*)Cv)[(size_t)(gm + r) * N + gn] = v;
            }
        }
    }
}

// ---------------------------------------------------------------------------
// Flash attention v8: QBLK 128 (2 Q-fragments per wave), no K-split.
// R4 lesson: resident waves are capped (~10/CU) regardless of grid size —
// K-split x2 bought exactly 0. So amortize per-wave instead: each wave owns
// TWO 16-row Q fragments. K/V staging, the 4 K ds_read_b128, the 4 V
// ds_read_b128, mask loads, barriers and loop overhead all serve 2x the
// output; MFMA per wave-tile 8->16; tile-iterations halve.
// mb is single-buffered but issued FIRST after the barrier (before the K/V
// prefetch) so waiting on mb doesn't drain the prefetch (vmcnt ordering).
// Direct bf16 output (no combine kernel).
// ---------------------------------------------------------------------------
__global__ __launch_bounds__(256, 4) void flash_attn8(
    const __hip_bfloat16* __restrict__ QKV,
    const float* __restrict__ mbias,
    __hip_bfloat16* __restrict__ O)
{
    __shared__ __hip_bfloat16 Ks[2][64 * 40];   // 10 KB
    __shared__ __hip_bfloat16 Vt[2][32 * 72];   // 9 KB (sigma-permuted cols)

    const int tid = threadIdx.x, lane = tid & 63, w = tid >> 6;
    const int l15 = lane & 15, qg = lane >> 4;

    // XCD-chunked swizzle (512 % 8 == 0 -> bijective): each XCD gets 64
    // consecutive logical blocks = 4 (b,h) groups (~2MB K/V) -> L2-resident.
    const int nwg = (int)gridDim.x;
    const int swz = ((int)blockIdx.x & 7) * (nwg >> 3) + ((int)blockIdx.x >> 3);
    const int qt = swz & 15;
    const int h  = (swz >> 4) & 15;
    const int b  = swz >> 8;
    const int q0 = qt * 128;

    // Q fragments (B-operand of swapped QK^T): rows q0+w*32+{l15, 16+l15}
    const bf16x8 qa0 = *(const bf16x8*)
        &QKV[(size_t)(b * SEQ + q0 + w * 32 + l15) * N_QKV + h * D_K + qg * 8];
    const bf16x8 qa1 = *(const bf16x8*)
        &QKV[(size_t)(b * SEQ + q0 + w * 32 + 16 + l15) * N_QKV + h * D_K + qg * 8];

    const int kv_k = tid >> 2, d0_k = (tid & 3) * 8;   // K staging coords
    const int kv_v = tid & 63, d0_v = (tid >> 6) * 8;  // V staging coords
    // sigma-permuted V column: kv = 32a+16hi+4g+r  ->  scol = 32a+8g+4hi+r
    const int scol_v = (kv_v & 32) + ((kv_v >> 2) & 3) * 8
                     + ((kv_v >> 4) & 1) * 4 + (kv_v & 3);

    const __hip_bfloat16* Kp = QKV + (size_t)b * SEQ * N_QKV + R_DIM + h * D_K;
    const __hip_bfloat16* Vp = QKV + (size_t)b * SEQ * N_QKV + 2 * R_DIM + h * D_K;
    const float* mb_base = mbias + b * SEQ;

    f32x4 oaccA[2] = {};   // qfrag0: rows w*32 + qg*4+r (+0)
    f32x4 oaccB[2] = {};   // qfrag1: rows w*32 + 16 + qg*4+r
    float rsum0 = 0.f, rsum1 = 0.f;

    uint4 kregA, kregB, vregA, vregB;

    // prologue: tile 0 into register set A
    kregA = *(const uint4*)&Kp[(size_t)kv_k * N_QKV + d0_k];
    vregA = *(const uint4*)&Vp[(size_t)kv_v * N_QKV + d0_v];

#define FA_EXP(SC, MB, PA, U0, U1, RS)                                          \
    {                                                                           \
        float p0 = __builtin_amdgcn_exp2f(SC[0] + MB.x);                        \
        float p1 = __builtin_amdgcn_exp2f(SC[1] + MB.y);                        \
        float p2 = __builtin_amdgcn_exp2f(SC[2] + MB.z);                        \
        float p3 = __builtin_amdgcn_exp2f(SC[3] + MB.w);                        \
        RS += (p0 + p1) + (p2 + p3);                                            \
        PA.u[U0] = cvt_pk_bf16(p0, p1);                                         \
        PA.u[U1] = cvt_pk_bf16(p2, p3);                                         \
    }

#define FA_ITER(KT, BUF, KREG, VREG, KREGN, VREGN)                              \
    {                                                                           \
        /* stage current tile (regs loaded last iter) into LDS[BUF] */          \
        *(uint4*)&Ks[BUF][kv_k * 40 + d0_k] = KREG;                             \
        { union { uint4 u; __hip_bfloat16 hv[8]; } vv; vv.u = VREG;             \
          _Pragma("unroll")                                                     \
          for (int j = 0; j < 8; j++)                                           \
              Vt[BUF][(d0_v + j) * 72 + scol_v] = vv.hv[j]; }                   \
        __syncthreads();                                                        \
        /* mask bias FIRST (oldest vmcnt) so its wait doesn't drain prefetch */ \
        float4 mb0 = *(const float4*)&mb_base[(KT) +  0 + qg * 4];              \
        float4 mb1 = *(const float4*)&mb_base[(KT) + 16 + qg * 4];              \
        float4 mb2 = *(const float4*)&mb_base[(KT) + 32 + qg * 4];              \
        float4 mb3 = *(const float4*)&mb_base[(KT) + 48 + qg * 4];              \
        /* prefetch next tile: a full iteration of compute covers it */         \
        if ((KT) + 64 < SEQ) {                                                  \
            KREGN = *(const uint4*)&Kp[(size_t)((KT) + 64 + kv_k) * N_QKV + d0_k]; \
            VREGN = *(const uint4*)&Vp[(size_t)((KT) + 64 + kv_v) * N_QKV + d0_v]; \
        }                                                                       \
        /* swapped QK^T: kb shared by both Q fragments */                       \
        f32x4 a0, a1, a2, a3, b0, b1, b2, b3;                                   \
        __builtin_amdgcn_s_setprio(1);                                          \
        { bf16x8 kb = *(const bf16x8*)&Ks[BUF][( 0 + l15) * 40 + qg * 8];       \
          f32x4 z = {};                                                         \
          a0 = __builtin_amdgcn_mfma_f32_16x16x32_bf16(kb, qa0, z, 0, 0, 0);    \
          b0 = __builtin_amdgcn_mfma_f32_16x16x32_bf16(kb, qa1, z, 0, 0, 0); }  \
        { bf16x8 kb = *(const bf16x8*)&Ks[BUF][(16 + l15) * 40 + qg * 8];       \
          f32x4 z = {};                                                         \
          a1 = __builtin_amdgcn_mfma_f32_16x16x32_bf16(kb, qa0, z, 0, 0, 0);    \
          b1 = __builtin_amdgcn_mfma_f32_16x16x32_bf16(kb, qa1, z, 0, 0, 0); }  \
        { bf16x8 kb = *(const bf16x8*)&Ks[BUF][(32 + l15) * 40 + qg * 8];       \
          f32x4 z = {};                                                         \
          a2 = __builtin_amdgcn_mfma_f32_16x16x32_bf16(kb, qa0, z, 0, 0, 0);    \
          b2 = __builtin_amdgcn_mfma_f32_16x16x32_bf16(kb, qa1, z, 0, 0, 0); }  \
        { bf16x8 kb = *(const bf16x8*)&Ks[BUF][(48 + l15) * 40 + qg * 8];       \
          f32x4 z = {};                                                         \
          a3 = __builtin_amdgcn_mfma_f32_16x16x32_bf16(kb, qa0, z, 0, 0, 0);    \
          b3 = __builtin_amdgcn_mfma_f32_16x16x32_bf16(kb, qa1, z, 0, 0, 0); }  \
        __builtin_amdgcn_s_setprio(0);                                          \
        /* exp2 + pack: lane's own dwords ARE the PV A-frag under sigma */      \
        union { unsigned u[4]; bf16x8 v; } paA0, paA1, paB0, paB1;              \
        FA_EXP(a0, mb0, paA0, 0, 1, rsum0)                                      \
        FA_EXP(a1, mb1, paA0, 2, 3, rsum0)                                      \
        FA_EXP(a2, mb2, paA1, 0, 1, rsum0)                                      \
        FA_EXP(a3, mb3, paA1, 2, 3, rsum0)                                      \
        FA_EXP(b0, mb0, paB0, 0, 1, rsum1)                                      \
        FA_EXP(b1, mb1, paB0, 2, 3, rsum1)                                      \
        FA_EXP(b2, mb2, paB1, 0, 1, rsum1)                                      \
        FA_EXP(b3, mb3, paB1, 2, 3, rsum1)                                      \
        /* PV: sigma-permuted Vt; vb shared by both Q fragments */              \
        __builtin_amdgcn_s_setprio(1);                                          \
        _Pragma("unroll")                                                       \
        for (int dt = 0; dt < 2; dt++) {                                        \
            const __hip_bfloat16* vrow = &Vt[BUF][(dt * 16 + l15) * 72];        \
            bf16x8 vb0 = *(const bf16x8*)&vrow[qg * 8];                         \
            bf16x8 vb1 = *(const bf16x8*)&vrow[32 + qg * 8];                    \
            oaccA[dt] = __builtin_amdgcn_mfma_f32_16x16x32_bf16(paA0.v, vb0, oaccA[dt], 0, 0, 0); \
            oaccA[dt] = __builtin_amdgcn_mfma_f32_16x16x32_bf16(paA1.v, vb1, oaccA[dt], 0, 0, 0); \
            oaccB[dt] = __builtin_amdgcn_mfma_f32_16x16x32_bf16(paB0.v, vb0, oaccB[dt], 0, 0, 0); \
            oaccB[dt] = __builtin_amdgcn_mfma_f32_16x16x32_bf16(paB1.v, vb1, oaccB[dt], 0, 0, 0); \
        }                                                                       \
        __builtin_amdgcn_s_setprio(0);                                          \
    }

    for (int kt = 0; kt < SEQ; kt += 128) {
        FA_ITER(kt,      0, kregA, vregA, kregB, vregB)
        FA_ITER(kt + 64, 1, kregB, vregB, kregA, vregA)
    }
#undef FA_ITER
#undef FA_EXP

    // row sums: lane (l15,qg) holds partial of row l15 (per qfrag)
    float s0 = rsum0, s1 = rsum1;
    s0 += __shfl_xor(s0, 16, 64);
    s0 += __shfl_xor(s0, 32, 64);
    s1 += __shfl_xor(s1, 16, 64);
    s1 += __shfl_xor(s1, 32, 64);

    // oacc layout: D[m=q][n=d]: row = qg*4+r, col = l15 (+16*dt)
    #pragma unroll
    for (int r = 0; r < 4; r++) {
        float invA = 1.0f / __shfl(s0, qg * 4 + r, 64);
        float invB = 1.0f / __shfl(s1, qg * 4 + r, 64);
        int rowA = q0 + w * 32 + qg * 4 + r;
        int rowB = rowA + 16;
        #pragma unroll
        for (int dt = 0; dt < 2; dt++) {
            O[(size_t)(b * SEQ + rowA) * R_DIM + h * D_K + dt * 16 + l15] =
                __float2bfloat16(oaccA[dt][r] * invA);
            O[(size_t)(b * SEQ + rowB) * R_DIM + h * D_K + dt * 16 + l15] =
                __float2bfloat16(oaccB[dt][r] * invB);
        }
    }
}

// ---------------------------------------------------------------------------
extern "C" void kernel_launch(void* const* d_in, const int* in_sizes, int n_in,
                              void* d_out, int out_size, void* d_ws, size_t ws_size,
                              hipStream_t stream)
{
    const float* x  = (const float*)d_in[0];
    const float* Wq = (const float*)d_in[1];
    const float* bq = (const float*)d_in[2];
    const float* Wk = (const float*)d_in[3];
    const float* bk = (const float*)d_in[4];
    const float* Wv = (const float*)d_in[5];
    const float* bv = (const float*)d_in[6];
    const float* Wo = (const float*)d_in[7];
    const float* bo = (const float*)d_in[8];
    const int* mask = (const int*)d_in[9];
    float* out = (float*)d_out;

    // ws layout (AO aliases xb: xb dead after the QKV GEMM)
    char* p = (char*)d_ws;
    __hip_bfloat16* xb     = (__hip_bfloat16*)p;                       // 16 MB
    __hip_bfloat16* AO     = xb;                                       // 4 MB alias
    __hip_bfloat16* Wqkvb  = (__hip_bfloat16*)(p + (16u << 20));       // 6 MB
    __hip_bfloat16* Wob    = (__hip_bfloat16*)(p + (22u << 20));       // 2 MB
    float*          biasq  = (float*)(p + (24u << 20));                // 6 KB
    float*          mbias  = (float*)(p + (24u << 20) + 8192);         // 16 KB
    __hip_bfloat16* QKVb   = (__hip_bfloat16*)(p + (25u << 20));       // 12 MB

    dim3 blk(256);
    hipLaunchKernelGGL(cvt_inputs, dim3(256, 6), blk, 0, stream,
                       x, xb, Wq, Wk, Wv, Wo, Wqkvb, Wob, bq, bk, bv, biasq, mask, mbias);
    hipLaunchKernelGGL((gemm_dma<true>), dim3(N_QKV / 64, M_ROWS / 128), blk, 0, stream,
                       xb, Wqkvb, biasq, QKVb, N_QKV, D_MODEL);
    hipLaunchKernelGGL(flash_attn8, dim3(B_SZ * N_HEADS * (SEQ / 128)), blk, 0, stream,
                       QKVb, mbias, AO);
    hipLaunchKernelGGL((gemm_dma<false>), dim3(D_MODEL / 64, M_ROWS / 128), blk, 0, stream,
                       AO, Wob, bo, out, D_MODEL, R_DIM);
}